// Round 7
// baseline (238.923 us; speedup 1.0000x reference)
//
#include <hip/hip_runtime.h>
#include <stdint.h>

#define ROW_LEN 2048
#define R4      512            // float4 per row
#define BLOCK   256            // 4 waves per block
#define NR      8              // rows per wave
#define EPS     1e-5f

typedef __attribute__((address_space(1))) unsigned int u32_g;
typedef __attribute__((address_space(3))) unsigned int u32_l;

// Register-free read: global -> LDS DMA, tracked only by vmcnt.
__device__ __forceinline__ void gload_lds16(const float4* src, float4* lds_dst) {
    __builtin_amdgcn_global_load_lds((const u32_g*)(const void*)src,
                                     (u32_l*)(void*)lds_dst, 16, 0, 0);
}

// Rounds 1-6 established: every structure with register-destination reads caps
// at ~2.5 TB/s because the compiler never keeps >2 loads in flight per lane
// (VGPR_Count 20-60 across all variants). Writes (no dest regs) hit 6.6 TB/s.
// This kernel makes READS register-free via global_load_lds: 8 x 1KB/wave/row
// staged into wave-private LDS slices, double-buffered, counted vmcnt(8) waits
// (never drain to 0 mid-loop). No __syncthreads — slices are wave-private.
__global__ __launch_bounds__(BLOCK) void RMSNorm_56607668961691_kernel(
    const float* __restrict__ x,
    const float* __restrict__ g,
    float* __restrict__ out)
{
    __shared__ float4 lds[2][BLOCK / 64][R4];   // 2 x 4 x 8KB = 64KB

    const int wave = threadIdx.x >> 6;
    const int lane = threadIdx.x & 63;
    const size_t wid  = (size_t)blockIdx.x * (BLOCK / 64) + wave;
    const size_t row0 = wid * NR;

    const float4* __restrict__ xr   = reinterpret_cast<const float4*>(x) + row0 * R4 + lane;
    float4* __restrict__       outr = reinterpret_cast<float4*>(out)     + row0 * R4 + lane;
    const float4* __restrict__ gv   = reinterpret_cast<const float4*>(g) + lane;

    // Prologue: stage row 0. Issued FIRST so these are never the newest-8
    // at the loop's vmcnt(8) wait.
    #pragma unroll
    for (int j = 0; j < 8; ++j)
        gload_lds16(xr + j * 64, &lds[0][wave][j * 64]);

    // g (8KB, L2-hot) into registers; compiler tracks these register deps.
    float4 gr[8];
    #pragma unroll
    for (int j = 0; j < 8; ++j) gr[j] = gv[j * 64];

    #pragma unroll 1
    for (int r = 0; r < NR; ++r) {
        const int cur = r & 1;

        // Counted wait: all but the newest 8 VMEM ops complete.
        // r==0: newest 8 = g loads  -> row 0 staging guaranteed done.
        // r>0 : newest 8 = stores of row r-1 -> row r staging guaranteed done.
        // Never vmcnt(0): next-row staging stays in flight across compute.
        asm volatile("s_waitcnt vmcnt(8)" ::: "memory");

        float4 v[8];
        #pragma unroll
        for (int j = 0; j < 8; ++j) v[j] = lds[cur][wave][j * 64 + lane];

        // Pin: ds_reads above, next-row staging below (keeps the wait minimal).
        __builtin_amdgcn_sched_barrier(0);

        if (r + 1 < NR) {
            const float4* xn = xr + (size_t)(r + 1) * R4;
            #pragma unroll
            for (int j = 0; j < 8; ++j)
                gload_lds16(xn + j * 64, &lds[cur ^ 1][wave][j * 64]);
        }

        float s0 = 0.f, s1 = 0.f, s2 = 0.f, s3 = 0.f;
        #pragma unroll
        for (int j = 0; j < 8; ++j) {
            s0 += v[j].x * v[j].x;
            s1 += v[j].y * v[j].y;
            s2 += v[j].z * v[j].z;
            s3 += v[j].w * v[j].w;
        }
        float ss = (s0 + s1) + (s2 + s3);

        #pragma unroll
        for (int off = 32; off > 0; off >>= 1)
            ss += __shfl_xor(ss, off, 64);

        const float scale = rsqrtf(ss * (1.0f / (float)ROW_LEN) + EPS);

        float4* o = outr + (size_t)r * R4;
        #pragma unroll
        for (int j = 0; j < 8; ++j) {
            float4 ov;
            ov.x = v[j].x * scale * gr[j].x;
            ov.y = v[j].y * scale * gr[j].y;
            ov.z = v[j].z * scale * gr[j].z;
            ov.w = v[j].w * scale * gr[j].w;
            o[j * 64] = ov;
        }
    }
}

extern "C" void kernel_launch(void* const* d_in, const int* in_sizes, int n_in,
                              void* d_out, int out_size, void* d_ws, size_t ws_size,
                              hipStream_t stream) {
    const float* x = (const float*)d_in[0];
    const float* g = (const float*)d_in[1];
    float* out = (float*)d_out;

    const int rows = in_sizes[0] / ROW_LEN;             // 16384
    const int grid = rows / ((BLOCK / 64) * NR);        // 512 blocks, 2/CU resident
    RMSNorm_56607668961691_kernel<<<grid, BLOCK, 0, stream>>>(x, g, out);
}

// Round 9
// 236.823 us; speedup vs baseline: 1.0089x; 1.0089x over previous
//
#include <hip/hip_runtime.h>

#define ROW_LEN 2048
#define R4      512            // float4 per row
#define BLOCK   256            // 4 waves per block
#define WAVES   (BLOCK / 64)
#define NR      8              // rows per wave
#define EPS     1e-5f

typedef __attribute__((address_space(1))) unsigned int u32_g;
typedef __attribute__((address_space(3))) unsigned int u32_l;

// Register-free read: global -> LDS DMA, tracked only by vmcnt. The compiler
// cannot shrink this burst (no destination VGPRs) and regalloc cannot corrupt
// it (no register results to copy) — the round-8 failure mode is impossible.
__device__ __forceinline__ void gload_lds16(const float4* src, float4* lds_dst) {
    __builtin_amdgcn_global_load_lds((const u32_g*)(const void*)src,
                                     (u32_l*)(void*)lds_dst, 16, 0, 0);
}

template<int N>
__device__ __forceinline__ void wait_vm() {
    asm volatile("s_waitcnt vmcnt(%0)" :: "n"(N) : "memory");
    __builtin_amdgcn_sched_barrier(0);   // rule #18: fence reg-only hoisting
}

// 2-row-deep register-free read pipeline, exact counted vmcnt (fix of round
// 7's drain bug: there, the wait's 8 allowed ops were the STORES, draining
// staging issued one compute-phase earlier -> 1-deep).
// Per-iteration VMEM order: stage(r+2)[8] | wait | ds_read(r) | store(r)[8].
// Ops after stage(r) at its wait: store(r-2) 8 + stage(r+1) 8 + store(r-1) 8
// + stage(r+2) 8 = 32 -> vmcnt(32) guarantees stage(r) done while leaving
// TWO staged rows + two rows of stores in flight. Edge rows: 16/24/.../24/16.
__global__ __launch_bounds__(BLOCK) void RMSNorm_56607668961691_kernel(
    const float* __restrict__ x,
    const float* __restrict__ g,
    float* __restrict__ out)
{
    __shared__ float4 lds[3][WAVES][R4];   // 3 x 4 x 8 KB = 96 KB -> 1 block/CU

    const int wave = threadIdx.x >> 6;
    const int lane = threadIdx.x & 63;
    const size_t wid  = (size_t)blockIdx.x * WAVES + wave;
    const size_t row0 = wid * NR;

    const float4* xr   = reinterpret_cast<const float4*>(x)   + row0 * R4 + lane;
    float4*       outr = reinterpret_cast<float4*>(out)       + row0 * R4 + lane;
    const float4* gv   = reinterpret_cast<const float4*>(g)   + lane;

    // g first: its (compiler-managed) wait can only land before staging grows.
    float4 gr[8];
    #pragma unroll
    for (int j = 0; j < 8; ++j) gr[j] = gv[j * 64];

    // Prologue: rows 0 and 1 staged -> 2 rows in flight before any wait.
    #pragma unroll
    for (int j = 0; j < 8; ++j) gload_lds16(xr + j * 64,      &lds[0][wave][j * 64]);
    #pragma unroll
    for (int j = 0; j < 8; ++j) gload_lds16(xr + R4 + j * 64, &lds[1][wave][j * 64]);

    #pragma unroll
    for (int r = 0; r < NR; ++r) {
        if (r + 2 < NR) {
            const float4* xn = xr + (size_t)(r + 2) * R4;
            float4* dst = &lds[(r + 2) % 3][wave][0];
            #pragma unroll
            for (int j = 0; j < 8; ++j) gload_lds16(xn + j * 64, dst + j * 64);
        }

        // Exact counted waits (r is compile-time: loop fully unrolled).
        if      (r == 0)      wait_vm<16>();
        else if (r == 1)      wait_vm<24>();
        else if (r <  NR - 2) wait_vm<32>();
        else if (r == NR - 2) wait_vm<24>();
        else                  wait_vm<16>();

        const float4* b = &lds[r % 3][wave][0];
        float4 v[8];
        #pragma unroll
        for (int j = 0; j < 8; ++j) v[j] = b[j * 64 + lane];

        float s0 = 0.f, s1 = 0.f, s2 = 0.f, s3 = 0.f;
        #pragma unroll
        for (int j = 0; j < 8; ++j) {
            s0 += v[j].x * v[j].x;
            s1 += v[j].y * v[j].y;
            s2 += v[j].z * v[j].z;
            s3 += v[j].w * v[j].w;
        }
        float ss = (s0 + s1) + (s2 + s3);

        #pragma unroll
        for (int off = 32; off > 0; off >>= 1)
            ss += __shfl_xor(ss, off, 64);

        const float scale = rsqrtf(ss * (1.0f / (float)ROW_LEN) + EPS);

        float4* o = outr + (size_t)r * R4;
        #pragma unroll
        for (int j = 0; j < 8; ++j) {
            float4 ov;
            ov.x = v[j].x * scale * gr[j].x;
            ov.y = v[j].y * scale * gr[j].y;
            ov.z = v[j].z * scale * gr[j].z;
            ov.w = v[j].w * scale * gr[j].w;
            o[j * 64] = ov;
        }

        // Pin iteration order: stores stay before next iteration's staging,
        // so the queue arithmetic above stays exact.
        asm volatile("" ::: "memory");
        __builtin_amdgcn_sched_barrier(0);
    }
}

extern "C" void kernel_launch(void* const* d_in, const int* in_sizes, int n_in,
                              void* d_out, int out_size, void* d_ws, size_t ws_size,
                              hipStream_t stream) {
    const float* x = (const float*)d_in[0];
    const float* g = (const float*)d_in[1];
    float* out = (float*)d_out;

    const int rows = in_sizes[0] / ROW_LEN;             // 16384
    const int grid = rows / (WAVES * NR);               // 512 blocks
    RMSNorm_56607668961691_kernel<<<grid, BLOCK, 0, stream>>>(x, g, out);
}